// Round 6
// baseline (209.057 us; speedup 1.0000x reference)
//
#include <hip/hip_runtime.h>
#include <hip/hip_bf16.h>
#include <cstdint>

// MxDNA deformable conv block, MI355X/gfx950.
// K2: W repack to FRAGMENT-LINEAR bf16 WB2[(kk*256+d)*32 + (kap&31)];
// K3: fused coef + gather-lerp + bf16 MFMA GEMM (M=65536, N=256, Kred=768).
// Round 5: XCD-aware bijective block swizzle (FETCH 203->69 MB).
// Round 6: BM64xBN256, 512thr, A+B LDS dbuf, token gathered once (62.5 us).
// Round 7/8 (REGRESSED): B direct-from-global in MFMA loop: -24 us. B stays in LDS.
// Round 9: coef fused into prologue + coalesced B staging from WB2 (157 us,
// gemm 75): bank conflicts 13.4M -- +4.7M from prologue wlds reads at
// sub*32+i*4 (all subs on bank-quad 0 -> 8-way).
// Round 10: (a) conflict-free wlds reads (offset i*16+sub*4: 4 distinct
// quads, broadcast within 16-lane groups); (b) wave tile 32x64 -> 64x64
// (BM=128, BN=256, 8 waves 2Mx4N, acc 4x4): LDS bytes/MFMA -35%
// (8 b128 reads + 24KB writes serve 128 wave-MFMA vs 6/8). LDS 60 KB,
// wlds aliased onto Bs[0] (dead before first packstore) -> 2 blocks/CU
// (same residency as R9). Grid 512: xcd owns batch xcd exactly.

#define N_TOK 8192
#define DIM   256
#define KW    768        // reduction length K*D
#define BM    128
#define BN    256
#define BK    32

typedef unsigned short u16;
typedef __attribute__((ext_vector_type(4))) float    floatx4;
typedef __attribute__((ext_vector_type(8))) __bf16   bf16x8;
typedef __attribute__((ext_vector_type(8))) u16      ushortx8;

__device__ __forceinline__ u16 f32_to_bf16_rne(float f) {
    uint32_t u = __float_as_uint(f);
    u += 0x7fffu + ((u >> 16) & 1u);
    return (u16)(u >> 16);
}

// ---------------- Kernel 2: repack weight, fragment-linear ----------------
// kap = k*256+e (reduction index); slice kk = kap>>5 holds a contiguous
// 16 KB block of 256 rows (d) x 32 shorts (kap&31).
__global__ __launch_bounds__(256) void packw_kernel(
    const float* __restrict__ W, u16* __restrict__ WB2)
{
    const int d = blockIdx.x;
    const int e = threadIdx.x;
#pragma unroll
    for (int k = 0; k < 3; ++k) {
        const int kap = k * 256 + e;
        WB2[((size_t)((kap >> 5) * 256 + d)) * 32 + (kap & 31)] =
            f32_to_bf16_rne(W[d * KW + e * 3 + k]);
    }
}

// ---------------- Kernel 3: fused coef + gather/lerp + MFMA GEMM ----------------
// block = 512 thr (8 waves), tile 128(M) x 256(N), BK=32, 24 K-iters.
// Wave tile 64x64 (2M x 4N): acc 4x4 frags. A+B in LDS dbuf (rows padded
// to 40 shorts), single end-of-iter barrier, register prefetch distance 2.
__global__ __launch_bounds__(512, 4) void deform_gemm_kernel(
    const float* __restrict__ x, const float* __restrict__ offw,
    const float* __restrict__ modw, const u16* __restrict__ WB2,
    float* __restrict__ out)
{
    __shared__ __align__(16) u16 As[2][BM * 40];   // 2 x 10240 B
    __shared__ __align__(16) u16 Bs[2][BN * 40];   // 2 x 20480 B
    float* wlds = (float*)&Bs[0][0];               // 6 KB alias, dead after prologue

    const int tid  = threadIdx.x;
    const int wave = tid >> 6;
    const int lane = tid & 63;

    // XCD-aware bijective swizzle: 512 blocks, hw xcd = b % 8.
    // XCD x owns mtiles [x*64, (x+1)*64) == batch x.
    const int raw   = blockIdx.x;
    const int xcd   = raw & 7;
    const int lidx  = raw >> 3;              // 0..63 within XCD
    const int mtile = xcd * 64 + lidx;
    const int t0 = mtile * BM;
    const float* xb = x + (size_t)(t0 / N_TOK) * N_TOK * DIM;  // batch base (BM | N_TOK)

    // staging roles: token tl (0..127), 8-float k-segment sub (0..3)
    const int tl  = tid >> 2;
    const int sub = tid & 3;

    const int wm = (wave & 1) * 64;   // wave M half
    const int wn = (wave >> 1) * 64;  // wave N quarter
    const int lrow = lane & 15;
    const int lq   = lane >> 4;

    // ---- fused coef computation for token t0+tl (4 threads/token) ----
    if (tid < 192)      ((float4*)wlds)[tid] = ((const float4*)offw)[tid];
    else if (tid < 384) ((float4*)wlds)[tid] = ((const float4*)modw)[tid - 192];
    __syncthreads();

    float s[6];
    {
        const float4* xr = (const float4*)(x + (size_t)(t0 + tl) * DIM);
        float4 xv[16];
#pragma unroll
        for (int i = 0; i < 16; ++i) xv[i] = xr[i * 4 + sub];   // offset i*16+sub*4 floats
#pragma unroll
        for (int w = 0; w < 6; ++w) {
            const float4* wr = (const float4*)(wlds + w * DIM);
            float a = 0.f;
#pragma unroll
            for (int i = 0; i < 16; ++i) {
                float4 wv = wr[i * 4 + sub];    // 4 distinct bank-quads: conflict-free
                a += xv[i].x * wv.x + xv[i].y * wv.y + xv[i].z * wv.z + xv[i].w * wv.w;
            }
            s[w] = a;
        }
    }
#pragma unroll
    for (int m = 1; m < 4; m <<= 1)
#pragma unroll
        for (int w = 0; w < 6; ++w) s[w] += __shfl_xor(s[w], m, 64);

    int fi0, fi1, fi2, ci0, ci1, ci2;
    float wa0, wa1, wa2, wc0, wc1, wc2;
    {
        const int n = (t0 + tl) & (N_TOK - 1);
#pragma unroll
        for (int k = 0; k < 3; ++k) {
            float pos   = (float)(n + k - 1) + s[k];
            bool  valid = (pos >= 0.0f) && (pos < (float)N_TOK);
            float ff = floorf(pos);
            ff = fminf(fmaxf(ff, 0.0f), (float)(N_TOK - 1));
            int   fi = (int)ff;
            int   ci = min(fi + 1, N_TOK - 1);
            float wc = pos - ff;
            float m  = valid ? (1.0f / (1.0f + expf(-s[3 + k]))) : 0.0f;
            float wa = (1.0f - wc) * m;
            float wcm = wc * m;
            if (k == 0) { fi0 = fi; ci0 = ci; wa0 = wa; wc0 = wcm; }
            if (k == 1) { fi1 = fi; ci1 = ci; wa1 = wa; wc1 = wcm; }
            if (k == 2) { fi2 = fi; ci2 = ci; wa2 = wa; wc2 = wcm; }
        }
    }
    __syncthreads();     // wlds reads complete before Bs[0] is overwritten

    // ---- pipeline registers (prefetch distance 2) ----
    float4 pf0, pf1, pc0, pc1;    // A gather (8 floats per thread)
    float  wA, wC;
    uint4  pb0, pb1;              // B staging (32 contiguous bytes per thread)

    auto loadg = [&](int kk) {
        const int tap = kk >> 3;
        const int fi = (tap == 0) ? fi0 : (tap == 1 ? fi1 : fi2);
        const int ci = (tap == 0) ? ci0 : (tap == 1 ? ci1 : ci2);
        wA = (tap == 0) ? wa0 : (tap == 1 ? wa1 : wa2);
        wC = (tap == 0) ? wc0 : (tap == 1 ? wc1 : wc2);
        const int e0 = (kk & 7) * 32 + sub * 8;
        const float* rf = xb + (size_t)fi * DIM + e0;
        const float* rc = xb + (size_t)ci * DIM + e0;
        pf0 = *(const float4*)rf;
        pf1 = *(const float4*)(rf + 4);
        pc0 = *(const float4*)rc;
        pc1 = *(const float4*)(rc + 4);
        // coalesced B staging read: slice kk is a contiguous 16 KB block
        const uint4* g = (const uint4*)(WB2 + (size_t)kk * 8192 + (size_t)tid * 16);
        pb0 = g[0];
        pb1 = g[1];
    };

    auto packstore = [&](int buf) {
        float r0 = wA * pf0.x + wC * pc0.x;
        float r1 = wA * pf0.y + wC * pc0.y;
        float r2 = wA * pf0.z + wC * pc0.z;
        float r3 = wA * pf0.w + wC * pc0.w;
        float r4 = wA * pf1.x + wC * pc1.x;
        float r5 = wA * pf1.y + wC * pc1.y;
        float r6 = wA * pf1.z + wC * pc1.z;
        float r7 = wA * pf1.w + wC * pc1.w;
        uint32_t p0 = __builtin_amdgcn_perm(__float_as_uint(r1), __float_as_uint(r0), 0x07060302u);
        uint32_t p1 = __builtin_amdgcn_perm(__float_as_uint(r3), __float_as_uint(r2), 0x07060302u);
        uint32_t p2 = __builtin_amdgcn_perm(__float_as_uint(r5), __float_as_uint(r4), 0x07060302u);
        uint32_t p3 = __builtin_amdgcn_perm(__float_as_uint(r7), __float_as_uint(r6), 0x07060302u);
        *(uint4*)&As[buf][tl * 40 + sub * 8] = make_uint4(p0, p1, p2, p3);
        // thread tid holds WB2 shorts [tid*16, tid*16+16): row d = tid>>1,
        // kap half = tid&1 -> proven Bs layout
        uint4* bdst = (uint4*)&Bs[buf][(tid >> 1) * 40 + (tid & 1) * 16];
        bdst[0] = pb0;
        bdst[1] = pb1;
    };

    // prologue: slice 0 -> buf0; prefetch slice 1 into registers
    loadg(0);
    packstore(0);
    loadg(1);

    floatx4 acc[4][4];
#pragma unroll
    for (int i = 0; i < 4; ++i)
#pragma unroll
        for (int j = 0; j < 4; ++j) acc[i][j] = (floatx4){0.f, 0.f, 0.f, 0.f};

    __syncthreads();                 // buf0 visible

    for (int kk = 0; kk < 24; ++kk) {
        const int cur = kk & 1;
        // fragments for slice kk from buf[cur]
        bf16x8 af[4], bfv[4];
#pragma unroll
        for (int i = 0; i < 4; ++i)
            af[i] = __builtin_bit_cast(bf16x8, *(const ushortx8*)&As[cur][(wm + i * 16 + lrow) * 40 + lq * 8]);
#pragma unroll
        for (int j = 0; j < 4; ++j)
            bfv[j] = __builtin_bit_cast(bf16x8, *(const ushortx8*)&Bs[cur][(wn + j * 16 + lrow) * 40 + lq * 8]);
        // stage slice kk+1 into the OTHER buffer
        if (kk < 23) packstore(cur ^ 1);
        // refill prefetch registers with slice kk+2
        if (kk < 22) loadg(kk + 2);
#pragma unroll
        for (int i = 0; i < 4; ++i) {
            acc[i][0] = __builtin_amdgcn_mfma_f32_16x16x32_bf16(af[i], bfv[0], acc[i][0], 0, 0, 0);
            acc[i][1] = __builtin_amdgcn_mfma_f32_16x16x32_bf16(af[i], bfv[1], acc[i][1], 0, 0, 0);
            acc[i][2] = __builtin_amdgcn_mfma_f32_16x16x32_bf16(af[i], bfv[2], acc[i][2], 0, 0, 0);
            acc[i][3] = __builtin_amdgcn_mfma_f32_16x16x32_bf16(af[i], bfv[3], acc[i][3], 0, 0, 0);
        }
        __syncthreads();             // writes(kk)->reads(kk+1), reads(kk)->writes(kk+1)
    }

    // ---- epilogue: C/D layout col = lane&15, row = (lane>>4)*4 + reg
#pragma unroll
    for (int i = 0; i < 4; ++i) {
#pragma unroll
        for (int r = 0; r < 4; ++r) {
            const int token = t0 + wm + i * 16 + lq * 4 + r;
            float* op = out + (size_t)token * DIM + wn + lrow;
#pragma unroll
            for (int j = 0; j < 4; ++j) op[j * 16] = acc[i][j][r];
        }
    }
}

extern "C" void kernel_launch(void* const* d_in, const int* in_sizes, int n_in,
                              void* d_out, int out_size, void* d_ws, size_t ws_size,
                              hipStream_t stream)
{
    const float* x    = (const float*)d_in[0];  // (8, 8192, 256)
    const float* offw = (const float*)d_in[1];  // (3, 256)
    const float* modw = (const float*)d_in[2];  // (3, 256)
    const float* W    = (const float*)d_in[3];  // (256, 256, 3)
    float* out = (float*)d_out;                 // (8, 8192, 256)

    const int tot_tok = 8 * N_TOK;              // 65536
    u16* WB2 = (u16*)d_ws;                      // 393,216 B fragment-linear weight

    packw_kernel<<<DIM, 256, 0, stream>>>(W, WB2);
    deform_gemm_kernel<<<tot_tok / BM, 512, 0, stream>>>(x, offw, modw, WB2, out);
}

// Round 7
// 206.095 us; speedup vs baseline: 1.0144x; 1.0144x over previous
//
#include <hip/hip_runtime.h>
#include <hip/hip_bf16.h>
#include <cstdint>

// MxDNA deformable conv block, MI355X/gfx950.
// K2: W repack to FRAGMENT-LINEAR bf16 WB2[(kk*256+d)*32 + (kap&31)];
// K3: fused coef + gather-lerp + bf16 MFMA GEMM (M=65536, N=256, Kred=768).
// Round 5: XCD-aware bijective block swizzle (FETCH 203->69 MB).
// Round 6: BM64xBN256, 512thr, A+B LDS dbuf, token gathered once (62.5 us).
// Round 7/8 (REGRESSED): B direct-from-global in MFMA loop: -24 us. B stays in LDS.
// Round 9: coef fused into prologue + coalesced B staging from WB2 (157 us,
// gemm 75); bank conflicts 13.4M (+4.7M from wlds reads: all 8 subs on
// bank-quad 0 -> 8-way).
// Round 10 (REGRESSED, gemm 120): 64x64 wave tile + xv[16] under the
// (512,4) 128-reg cap -> scratch spills (WRITE 65->205 MB, FETCH 74->162 MB
// with identical store patterns). Conflicts did drop (13.4->5.5M): theory
// right, vehicle wrong. Lesson: keep live set well under the cap.
// Round 11: R9 verbatim + ONLY the conflict fix, register-neutral: rotate
// wlds read order by sub (ii=(i+sub)&7) -> per instruction the 8 sub-groups
// hit 8 distinct bank-quads (conflict-free); same-address lanes across the
// 8 tokens broadcast for free.

#define N_TOK 8192
#define DIM   256
#define KW    768        // reduction length K*D
#define BM    64
#define BN    256
#define BK    32

typedef unsigned short u16;
typedef __attribute__((ext_vector_type(4))) float    floatx4;
typedef __attribute__((ext_vector_type(8))) __bf16   bf16x8;
typedef __attribute__((ext_vector_type(8))) u16      ushortx8;

__device__ __forceinline__ u16 f32_to_bf16_rne(float f) {
    uint32_t u = __float_as_uint(f);
    u += 0x7fffu + ((u >> 16) & 1u);
    return (u16)(u >> 16);
}

// ---------------- Kernel 2: repack weight, fragment-linear ----------------
// kap = k*256+e (reduction index); slice kk = kap>>5 holds a contiguous
// 16 KB block of 256 rows (d) x 32 shorts (kap&31).
__global__ __launch_bounds__(256) void packw_kernel(
    const float* __restrict__ W, u16* __restrict__ WB2)
{
    const int d = blockIdx.x;
    const int e = threadIdx.x;
#pragma unroll
    for (int k = 0; k < 3; ++k) {
        const int kap = k * 256 + e;
        WB2[((size_t)((kap >> 5) * 256 + d)) * 32 + (kap & 31)] =
            f32_to_bf16_rne(W[d * KW + e * 3 + k]);
    }
}

// ---------------- Kernel 3: fused coef + gather/lerp + MFMA GEMM ----------------
// block = 512 thr (8 waves), tile 64(M) x 256(N), BK=32, 24 K-iters.
// Wave tile 32x64: acc 2x4 frags. A+B in LDS dbuf (rows padded to 40
// shorts), single end-of-iter barrier, register prefetch distance 2.
__global__ __launch_bounds__(512, 4) void deform_gemm_kernel(
    const float* __restrict__ x, const float* __restrict__ offw,
    const float* __restrict__ modw, const u16* __restrict__ WB2,
    float* __restrict__ out)
{
    __shared__ __align__(16) u16   As[2][BM * 40];   // 2 x  5120 B
    __shared__ __align__(16) u16   Bs[2][BN * 40];   // 2 x 20480 B
    __shared__ __align__(16) float wlds[6 * DIM];    // offw rows 0-2, modw rows 3-5

    const int tid  = threadIdx.x;
    const int wave = tid >> 6;
    const int lane = tid & 63;

    // XCD-aware bijective swizzle: 1024 blocks, hw xcd = b % 8.
    // XCD x owns mtiles [x*128, (x+1)*128) == batch x.
    const int raw   = blockIdx.x;
    const int xcd   = raw & 7;
    const int lidx  = raw >> 3;              // 0..127 within XCD
    const int mtile = xcd * 128 + lidx;
    const int t0 = mtile * BM;
    const float* xb = x + (size_t)(t0 / N_TOK) * N_TOK * DIM;  // batch base (BM | N_TOK)

    // A staging role: token tl (0..63), 4-float column segment sub (0..7)
    const int tl  = tid >> 3;
    const int sub = tid & 7;

    const int wm = (wave & 1) * 32;   // wave M half
    const int wn = (wave >> 1) * 64;  // wave N quarter
    const int lrow = lane & 15;
    const int lq   = lane >> 4;

    // ---- fused coef computation for token t0+tl (8 threads/token) ----
    if (tid < 192)      ((float4*)wlds)[tid] = ((const float4*)offw)[tid];
    else if (tid < 384) ((float4*)wlds)[tid] = ((const float4*)modw)[tid - 192];
    __syncthreads();

    float s[6];
    {
        const float* xr = x + (size_t)(t0 + tl) * DIM + sub * 32;
        float4 xv[8];
#pragma unroll
        for (int i = 0; i < 8; ++i) xv[i] = ((const float4*)xr)[i];
#pragma unroll
        for (int w = 0; w < 6; ++w) {
            const float4* wr = (const float4*)(wlds + w * DIM + sub * 32);
            float a = 0.f;
#pragma unroll
            for (int i = 0; i < 8; ++i) {
                const int ii = (i + sub) & 7;   // rotated: 8 subs -> 8 distinct bank-quads
                float4 wv = wr[ii];
                a += xv[ii].x * wv.x + xv[ii].y * wv.y + xv[ii].z * wv.z + xv[ii].w * wv.w;
            }
            s[w] = a;
        }
    }
#pragma unroll
    for (int m = 1; m < 8; m <<= 1)
#pragma unroll
        for (int w = 0; w < 6; ++w) s[w] += __shfl_xor(s[w], m, 64);

    int fi0, fi1, fi2, ci0, ci1, ci2;
    float wa0, wa1, wa2, wc0, wc1, wc2;
    {
        const int n = (t0 + tl) & (N_TOK - 1);
#pragma unroll
        for (int k = 0; k < 3; ++k) {
            float pos   = (float)(n + k - 1) + s[k];
            bool  valid = (pos >= 0.0f) && (pos < (float)N_TOK);
            float ff = floorf(pos);
            ff = fminf(fmaxf(ff, 0.0f), (float)(N_TOK - 1));
            int   fi = (int)ff;
            int   ci = min(fi + 1, N_TOK - 1);
            float wc = pos - ff;
            float m  = valid ? (1.0f / (1.0f + expf(-s[3 + k]))) : 0.0f;
            float wa = (1.0f - wc) * m;
            float wcm = wc * m;
            if (k == 0) { fi0 = fi; ci0 = ci; wa0 = wa; wc0 = wcm; }
            if (k == 1) { fi1 = fi; ci1 = ci; wa1 = wa; wc1 = wcm; }
            if (k == 2) { fi2 = fi; ci2 = ci; wa2 = wa; wc2 = wcm; }
        }
    }

    // ---- pipeline registers (prefetch distance 2) ----
    float4 pf, pc;       // A gather
    float  wA, wC;
    uint4  pb0, pb1;     // B staging (32 contiguous bytes per thread)

    auto loadg = [&](int kk) {
        const int tap = kk >> 3;
        const int fi = (tap == 0) ? fi0 : (tap == 1 ? fi1 : fi2);
        const int ci = (tap == 0) ? ci0 : (tap == 1 ? ci1 : ci2);
        wA = (tap == 0) ? wa0 : (tap == 1 ? wa1 : wa2);
        wC = (tap == 0) ? wc0 : (tap == 1 ? wc1 : wc2);
        const int e0 = (kk & 7) * 32 + sub * 4;
        pf = *(const float4*)(xb + (size_t)fi * DIM + e0);
        pc = *(const float4*)(xb + (size_t)ci * DIM + e0);
        // coalesced B staging read: slice kk is a contiguous 16 KB block
        const uint4* g = (const uint4*)(WB2 + (size_t)kk * 8192 + (size_t)tid * 16);
        pb0 = g[0];
        pb1 = g[1];
    };

    auto packstore = [&](int buf) {
        float r0 = wA * pf.x + wC * pc.x;
        float r1 = wA * pf.y + wC * pc.y;
        float r2 = wA * pf.z + wC * pc.z;
        float r3 = wA * pf.w + wC * pc.w;
        uint32_t p0 = __builtin_amdgcn_perm(__float_as_uint(r1), __float_as_uint(r0), 0x07060302u);
        uint32_t p1 = __builtin_amdgcn_perm(__float_as_uint(r3), __float_as_uint(r2), 0x07060302u);
        *(uint2*)&As[buf][tl * 40 + sub * 4] = make_uint2(p0, p1);
        // thread tid holds WB2 shorts [tid*16, tid*16+16): row d = tid>>1,
        // kap half = tid&1 -> proven Bs layout
        uint4* bdst = (uint4*)&Bs[buf][(tid >> 1) * 40 + (tid & 1) * 16];
        bdst[0] = pb0;
        bdst[1] = pb1;
    };

    // prologue: slice 0 -> buf0; prefetch slice 1 into registers
    loadg(0);
    packstore(0);
    loadg(1);

    floatx4 acc[2][4];
#pragma unroll
    for (int i = 0; i < 2; ++i)
#pragma unroll
        for (int j = 0; j < 4; ++j) acc[i][j] = (floatx4){0.f, 0.f, 0.f, 0.f};

    __syncthreads();                 // buf0 visible

    for (int kk = 0; kk < 24; ++kk) {
        const int cur = kk & 1;
        // fragments for slice kk from buf[cur]
        bf16x8 af[2], bfv[4];
#pragma unroll
        for (int i = 0; i < 2; ++i)
            af[i] = __builtin_bit_cast(bf16x8, *(const ushortx8*)&As[cur][(wm + i * 16 + lrow) * 40 + lq * 8]);
#pragma unroll
        for (int j = 0; j < 4; ++j)
            bfv[j] = __builtin_bit_cast(bf16x8, *(const ushortx8*)&Bs[cur][(wn + j * 16 + lrow) * 40 + lq * 8]);
        // stage slice kk+1 into the OTHER buffer
        if (kk < 23) packstore(cur ^ 1);
        // refill prefetch registers with slice kk+2
        if (kk < 22) loadg(kk + 2);
#pragma unroll
        for (int i = 0; i < 2; ++i) {
            acc[i][0] = __builtin_amdgcn_mfma_f32_16x16x32_bf16(af[i], bfv[0], acc[i][0], 0, 0, 0);
            acc[i][1] = __builtin_amdgcn_mfma_f32_16x16x32_bf16(af[i], bfv[1], acc[i][1], 0, 0, 0);
            acc[i][2] = __builtin_amdgcn_mfma_f32_16x16x32_bf16(af[i], bfv[2], acc[i][2], 0, 0, 0);
            acc[i][3] = __builtin_amdgcn_mfma_f32_16x16x32_bf16(af[i], bfv[3], acc[i][3], 0, 0, 0);
        }
        __syncthreads();             // writes(kk)->reads(kk+1), reads(kk)->writes(kk+1)
    }

    // ---- epilogue: C/D layout col = lane&15, row = (lane>>4)*4 + reg
#pragma unroll
    for (int i = 0; i < 2; ++i) {
#pragma unroll
        for (int r = 0; r < 4; ++r) {
            const int token = t0 + wm + i * 16 + lq * 4 + r;
            float* op = out + (size_t)token * DIM + wn + lrow;
#pragma unroll
            for (int j = 0; j < 4; ++j) op[j * 16] = acc[i][j][r];
        }
    }
}

extern "C" void kernel_launch(void* const* d_in, const int* in_sizes, int n_in,
                              void* d_out, int out_size, void* d_ws, size_t ws_size,
                              hipStream_t stream)
{
    const float* x    = (const float*)d_in[0];  // (8, 8192, 256)
    const float* offw = (const float*)d_in[1];  // (3, 256)
    const float* modw = (const float*)d_in[2];  // (3, 256)
    const float* W    = (const float*)d_in[3];  // (256, 256, 3)
    float* out = (float*)d_out;                 // (8, 8192, 256)

    const int tot_tok = 8 * N_TOK;              // 65536
    u16* WB2 = (u16*)d_ws;                      // 393,216 B fragment-linear weight

    packw_kernel<<<DIM, 256, 0, stream>>>(W, WB2);
    deform_gemm_kernel<<<tot_tok / BM, 512, 0, stream>>>(x, offw, modw, WB2, out);
}

// Round 8
// 159.016 us; speedup vs baseline: 1.3147x; 1.2961x over previous
//
#include <hip/hip_runtime.h>
#include <hip/hip_bf16.h>
#include <cstdint>

// MxDNA deformable conv block, MI355X/gfx950.
// K2: W repack to FRAGMENT-LINEAR bf16 WB2[(kk*256+d)*32 + (kap&31)];
// K3: fused coef + gather-lerp + bf16 MFMA GEMM (M=65536, N=256, Kred=768).
// Round 5: XCD-aware bijective block swizzle (FETCH 203->69 MB).
// Round 6: BM64xBN256, 512thr, A+B LDS dbuf, token gathered once (62.5 us).
// Round 7/8 (REGRESSED): B direct-from-global in MFMA loop. B stays in LDS.
// Round 9: coef fused into prologue + coalesced B staging from WB2
// (157 us total, gemm 75; conflicts 13.4M, +4.7M from 8-way wlds reads).
// Round 10 (REGRESSED): 64x64 wave tile spilled under the 128-reg cap.
// Round 11 (REGRESSED, gemm 120): conflict fix via xv[(i+sub)&7] --
// RUNTIME-INDEXED REGISTER ARRAY -> xv lives in scratch (WRITE +65.5 MB
// exactly, FETCH +59 MB). Conflicts DID drop 13.4->8.65M: analysis right,
// vehicle violated rule "static indices only for register arrays".
// Round 12: R9 + address-only rotation: xv[i] = xr[(i+sub)&7] (static reg
// index, rotated ADDRESS) paired with wr[(i+sub)&7] -- same-slot data
// multiplied together, sum order rotated (R11 proved tolerance-safe).
// LDS: for fixed i the 8 subs hit 8 distinct bank quads -> conflict-free.

#define N_TOK 8192
#define DIM   256
#define KW    768        // reduction length K*D
#define BM    64
#define BN    256
#define BK    32

typedef unsigned short u16;
typedef __attribute__((ext_vector_type(4))) float    floatx4;
typedef __attribute__((ext_vector_type(8))) __bf16   bf16x8;
typedef __attribute__((ext_vector_type(8))) u16      ushortx8;

__device__ __forceinline__ u16 f32_to_bf16_rne(float f) {
    uint32_t u = __float_as_uint(f);
    u += 0x7fffu + ((u >> 16) & 1u);
    return (u16)(u >> 16);
}

// ---------------- Kernel 2: repack weight, fragment-linear ----------------
// kap = k*256+e (reduction index); slice kk = kap>>5 holds a contiguous
// 16 KB block of 256 rows (d) x 32 shorts (kap&31).
__global__ __launch_bounds__(256) void packw_kernel(
    const float* __restrict__ W, u16* __restrict__ WB2)
{
    const int d = blockIdx.x;
    const int e = threadIdx.x;
#pragma unroll
    for (int k = 0; k < 3; ++k) {
        const int kap = k * 256 + e;
        WB2[((size_t)((kap >> 5) * 256 + d)) * 32 + (kap & 31)] =
            f32_to_bf16_rne(W[d * KW + e * 3 + k]);
    }
}

// ---------------- Kernel 3: fused coef + gather/lerp + MFMA GEMM ----------------
// block = 512 thr (8 waves), tile 64(M) x 256(N), BK=32, 24 K-iters.
// Wave tile 32x64: acc 2x4 frags. A+B in LDS dbuf (rows padded to 40
// shorts), single end-of-iter barrier, register prefetch distance 2.
__global__ __launch_bounds__(512, 4) void deform_gemm_kernel(
    const float* __restrict__ x, const float* __restrict__ offw,
    const float* __restrict__ modw, const u16* __restrict__ WB2,
    float* __restrict__ out)
{
    __shared__ __align__(16) u16   As[2][BM * 40];   // 2 x  5120 B
    __shared__ __align__(16) u16   Bs[2][BN * 40];   // 2 x 20480 B
    __shared__ __align__(16) float wlds[6 * DIM];    // offw rows 0-2, modw rows 3-5

    const int tid  = threadIdx.x;
    const int wave = tid >> 6;
    const int lane = tid & 63;

    // XCD-aware bijective swizzle: 1024 blocks, hw xcd = b % 8.
    // XCD x owns mtiles [x*128, (x+1)*128) == batch x.
    const int raw   = blockIdx.x;
    const int xcd   = raw & 7;
    const int lidx  = raw >> 3;              // 0..127 within XCD
    const int mtile = xcd * 128 + lidx;
    const int t0 = mtile * BM;
    const float* xb = x + (size_t)(t0 / N_TOK) * N_TOK * DIM;  // batch base (BM | N_TOK)

    // A staging role: token tl (0..63), 4-float column segment sub (0..7)
    const int tl  = tid >> 3;
    const int sub = tid & 7;

    const int wm = (wave & 1) * 32;   // wave M half
    const int wn = (wave >> 1) * 64;  // wave N quarter
    const int lrow = lane & 15;
    const int lq   = lane >> 4;

    // ---- fused coef computation for token t0+tl (8 threads/token) ----
    if (tid < 192)      ((float4*)wlds)[tid] = ((const float4*)offw)[tid];
    else if (tid < 384) ((float4*)wlds)[tid] = ((const float4*)modw)[tid - 192];
    __syncthreads();

    float s[6];
    {
        const float* xr = x + (size_t)(t0 + tl) * DIM + sub * 32;
        float4 xv[8];
#pragma unroll
        for (int i = 0; i < 8; ++i)
            xv[i] = ((const float4*)xr)[(i + sub) & 7];   // rotated ADDRESS, static reg index
#pragma unroll
        for (int w = 0; w < 6; ++w) {
            const float4* wr = (const float4*)(wlds + w * DIM + sub * 32);
            float a = 0.f;
#pragma unroll
            for (int i = 0; i < 8; ++i) {
                float4 wv = wr[(i + sub) & 7];   // rotated LDS address: 8 subs -> 8 bank quads
                a += xv[i].x * wv.x + xv[i].y * wv.y + xv[i].z * wv.z + xv[i].w * wv.w;
            }
            s[w] = a;
        }
    }
#pragma unroll
    for (int m = 1; m < 8; m <<= 1)
#pragma unroll
        for (int w = 0; w < 6; ++w) s[w] += __shfl_xor(s[w], m, 64);

    int fi0, fi1, fi2, ci0, ci1, ci2;
    float wa0, wa1, wa2, wc0, wc1, wc2;
    {
        const int n = (t0 + tl) & (N_TOK - 1);
#pragma unroll
        for (int k = 0; k < 3; ++k) {
            float pos   = (float)(n + k - 1) + s[k];
            bool  valid = (pos >= 0.0f) && (pos < (float)N_TOK);
            float ff = floorf(pos);
            ff = fminf(fmaxf(ff, 0.0f), (float)(N_TOK - 1));
            int   fi = (int)ff;
            int   ci = min(fi + 1, N_TOK - 1);
            float wc = pos - ff;
            float m  = valid ? (1.0f / (1.0f + expf(-s[3 + k]))) : 0.0f;
            float wa = (1.0f - wc) * m;
            float wcm = wc * m;
            if (k == 0) { fi0 = fi; ci0 = ci; wa0 = wa; wc0 = wcm; }
            if (k == 1) { fi1 = fi; ci1 = ci; wa1 = wa; wc1 = wcm; }
            if (k == 2) { fi2 = fi; ci2 = ci; wa2 = wa; wc2 = wcm; }
        }
    }

    // ---- pipeline registers (prefetch distance 2) ----
    float4 pf, pc;       // A gather
    float  wA, wC;
    uint4  pb0, pb1;     // B staging (32 contiguous bytes per thread)

    auto loadg = [&](int kk) {
        const int tap = kk >> 3;
        const int fi = (tap == 0) ? fi0 : (tap == 1 ? fi1 : fi2);
        const int ci = (tap == 0) ? ci0 : (tap == 1 ? ci1 : ci2);
        wA = (tap == 0) ? wa0 : (tap == 1 ? wa1 : wa2);
        wC = (tap == 0) ? wc0 : (tap == 1 ? wc1 : wc2);
        const int e0 = (kk & 7) * 32 + sub * 4;
        pf = *(const float4*)(xb + (size_t)fi * DIM + e0);
        pc = *(const float4*)(xb + (size_t)ci * DIM + e0);
        // coalesced B staging read: slice kk is a contiguous 16 KB block
        const uint4* g = (const uint4*)(WB2 + (size_t)kk * 8192 + (size_t)tid * 16);
        pb0 = g[0];
        pb1 = g[1];
    };

    auto packstore = [&](int buf) {
        float r0 = wA * pf.x + wC * pc.x;
        float r1 = wA * pf.y + wC * pc.y;
        float r2 = wA * pf.z + wC * pc.z;
        float r3 = wA * pf.w + wC * pc.w;
        uint32_t p0 = __builtin_amdgcn_perm(__float_as_uint(r1), __float_as_uint(r0), 0x07060302u);
        uint32_t p1 = __builtin_amdgcn_perm(__float_as_uint(r3), __float_as_uint(r2), 0x07060302u);
        *(uint2*)&As[buf][tl * 40 + sub * 4] = make_uint2(p0, p1);
        // thread tid holds WB2 shorts [tid*16, tid*16+16): row d = tid>>1,
        // kap half = tid&1 -> proven Bs layout
        uint4* bdst = (uint4*)&Bs[buf][(tid >> 1) * 40 + (tid & 1) * 16];
        bdst[0] = pb0;
        bdst[1] = pb1;
    };

    // prologue: slice 0 -> buf0; prefetch slice 1 into registers
    loadg(0);
    packstore(0);
    loadg(1);

    floatx4 acc[2][4];
#pragma unroll
    for (int i = 0; i < 2; ++i)
#pragma unroll
        for (int j = 0; j < 4; ++j) acc[i][j] = (floatx4){0.f, 0.f, 0.f, 0.f};

    __syncthreads();                 // buf0 visible

    for (int kk = 0; kk < 24; ++kk) {
        const int cur = kk & 1;
        // fragments for slice kk from buf[cur]
        bf16x8 af[2], bfv[4];
#pragma unroll
        for (int i = 0; i < 2; ++i)
            af[i] = __builtin_bit_cast(bf16x8, *(const ushortx8*)&As[cur][(wm + i * 16 + lrow) * 40 + lq * 8]);
#pragma unroll
        for (int j = 0; j < 4; ++j)
            bfv[j] = __builtin_bit_cast(bf16x8, *(const ushortx8*)&Bs[cur][(wn + j * 16 + lrow) * 40 + lq * 8]);
        // stage slice kk+1 into the OTHER buffer
        if (kk < 23) packstore(cur ^ 1);
        // refill prefetch registers with slice kk+2
        if (kk < 22) loadg(kk + 2);
#pragma unroll
        for (int i = 0; i < 2; ++i) {
            acc[i][0] = __builtin_amdgcn_mfma_f32_16x16x32_bf16(af[i], bfv[0], acc[i][0], 0, 0, 0);
            acc[i][1] = __builtin_amdgcn_mfma_f32_16x16x32_bf16(af[i], bfv[1], acc[i][1], 0, 0, 0);
            acc[i][2] = __builtin_amdgcn_mfma_f32_16x16x32_bf16(af[i], bfv[2], acc[i][2], 0, 0, 0);
            acc[i][3] = __builtin_amdgcn_mfma_f32_16x16x32_bf16(af[i], bfv[3], acc[i][3], 0, 0, 0);
        }
        __syncthreads();             // writes(kk)->reads(kk+1), reads(kk)->writes(kk+1)
    }

    // ---- epilogue: C/D layout col = lane&15, row = (lane>>4)*4 + reg
#pragma unroll
    for (int i = 0; i < 2; ++i) {
#pragma unroll
        for (int r = 0; r < 4; ++r) {
            const int token = t0 + wm + i * 16 + lq * 4 + r;
            float* op = out + (size_t)token * DIM + wn + lrow;
#pragma unroll
            for (int j = 0; j < 4; ++j) op[j * 16] = acc[i][j][r];
        }
    }
}

extern "C" void kernel_launch(void* const* d_in, const int* in_sizes, int n_in,
                              void* d_out, int out_size, void* d_ws, size_t ws_size,
                              hipStream_t stream)
{
    const float* x    = (const float*)d_in[0];  // (8, 8192, 256)
    const float* offw = (const float*)d_in[1];  // (3, 256)
    const float* modw = (const float*)d_in[2];  // (3, 256)
    const float* W    = (const float*)d_in[3];  // (256, 256, 3)
    float* out = (float*)d_out;                 // (8, 8192, 256)

    const int tot_tok = 8 * N_TOK;              // 65536
    u16* WB2 = (u16*)d_ws;                      // 393,216 B fragment-linear weight

    packw_kernel<<<DIM, 256, 0, stream>>>(W, WB2);
    deform_gemm_kernel<<<tot_tok / BM, 512, 0, stream>>>(x, offw, modw, WB2, out);
}

// Round 9
// 157.948 us; speedup vs baseline: 1.3236x; 1.0068x over previous
//
#include <hip/hip_runtime.h>
#include <hip/hip_bf16.h>
#include <cstdint>

// MxDNA deformable conv block, MI355X/gfx950.
// K2: W repack to FRAGMENT-LINEAR bf16 WB2[(kk*256+d)*32 + (kap&31)];
// K3: fused coef + gather-lerp + bf16 MFMA GEMM (M=65536, N=256, Kred=768).
// Round 5: XCD swizzle. Round 6: BM64xBN256 512thr (62.5us gemm).
// Round 7/8: B direct-from-global regressed; B stays in LDS.
// Round 9: coef fusion + coalesced WB2 staging (157us total, gemm 75).
// Round 10/11: spill lessons (reg cap, static indices only).
// Round 12: conflict fix via address rotation: conflicts 13.4->8.65M,
// dur UNCHANGED -> conflicts are off the critical path. Stop chasing them.
// Round 13: TRUE prefetch distance. Old loop: packstore reads pf/pc, then
// loadg(kk+2) overwrites the SAME regs (WAR) -> global loads issue ~100cyc
// before the barrier, and hipcc drains vmcnt(0) at every __syncthreads ->
// each of 24 iters pays near-full gather latency. Fix: ping-pong register
// sets A/B (statically named, rule #20), loop unrolled x2, loads issue at
// TOP of iter -> full iter body (~800cyc LDS+MFMA) covers the drain.

#define N_TOK 8192
#define DIM   256
#define KW    768        // reduction length K*D
#define BM    64
#define BN    256
#define BK    32

typedef unsigned short u16;
typedef __attribute__((ext_vector_type(4))) float    floatx4;
typedef __attribute__((ext_vector_type(8))) __bf16   bf16x8;
typedef __attribute__((ext_vector_type(8))) u16      ushortx8;

__device__ __forceinline__ u16 f32_to_bf16_rne(float f) {
    uint32_t u = __float_as_uint(f);
    u += 0x7fffu + ((u >> 16) & 1u);
    return (u16)(u >> 16);
}

// ---------------- Kernel 2: repack weight, fragment-linear ----------------
// kap = k*256+e (reduction index); slice kk = kap>>5 holds a contiguous
// 16 KB block of 256 rows (d) x 32 shorts (kap&31).
__global__ __launch_bounds__(256) void packw_kernel(
    const float* __restrict__ W, u16* __restrict__ WB2)
{
    const int d = blockIdx.x;
    const int e = threadIdx.x;
#pragma unroll
    for (int k = 0; k < 3; ++k) {
        const int kap = k * 256 + e;
        WB2[((size_t)((kap >> 5) * 256 + d)) * 32 + (kap & 31)] =
            f32_to_bf16_rne(W[d * KW + e * 3 + k]);
    }
}

// ---------------- Kernel 3: fused coef + gather/lerp + MFMA GEMM ----------------
// block = 512 thr (8 waves), tile 64(M) x 256(N), BK=32, 24 K-iters.
// Wave tile 32x64: acc 2x4 frags. A+B in LDS dbuf (rows padded to 40
// shorts), single end-of-iter barrier, ping-pong prefetch register sets.
__global__ __launch_bounds__(512, 4) void deform_gemm_kernel(
    const float* __restrict__ x, const float* __restrict__ offw,
    const float* __restrict__ modw, const u16* __restrict__ WB2,
    float* __restrict__ out)
{
    __shared__ __align__(16) u16   As[2][BM * 40];   // 2 x  5120 B
    __shared__ __align__(16) u16   Bs[2][BN * 40];   // 2 x 20480 B
    __shared__ __align__(16) float wlds[6 * DIM];    // offw rows 0-2, modw rows 3-5

    const int tid  = threadIdx.x;
    const int wave = tid >> 6;
    const int lane = tid & 63;

    // XCD-aware bijective swizzle: 1024 blocks, hw xcd = b % 8.
    const int raw   = blockIdx.x;
    const int xcd   = raw & 7;
    const int lidx  = raw >> 3;              // 0..127 within XCD
    const int mtile = xcd * 128 + lidx;
    const int t0 = mtile * BM;
    const float* xb = x + (size_t)(t0 / N_TOK) * N_TOK * DIM;  // batch base (BM | N_TOK)

    // A staging role: token tl (0..63), 4-float column segment sub (0..7)
    const int tl  = tid >> 3;
    const int sub = tid & 7;

    const int wm = (wave & 1) * 32;   // wave M half
    const int wn = (wave >> 1) * 64;  // wave N quarter
    const int lrow = lane & 15;
    const int lq   = lane >> 4;

    // ---- fused coef computation for token t0+tl (8 threads/token) ----
    if (tid < 192)      ((float4*)wlds)[tid] = ((const float4*)offw)[tid];
    else if (tid < 384) ((float4*)wlds)[tid] = ((const float4*)modw)[tid - 192];
    __syncthreads();

    float s[6];
    {
        const float* xr = x + (size_t)(t0 + tl) * DIM + sub * 32;
        float4 xv[8];
#pragma unroll
        for (int i = 0; i < 8; ++i)
            xv[i] = ((const float4*)xr)[(i + sub) & 7];   // rotated ADDRESS, static reg index
#pragma unroll
        for (int w = 0; w < 6; ++w) {
            const float4* wr = (const float4*)(wlds + w * DIM + sub * 32);
            float a = 0.f;
#pragma unroll
            for (int i = 0; i < 8; ++i) {
                float4 wv = wr[(i + sub) & 7];   // rotated LDS address: conflict-free
                a += xv[i].x * wv.x + xv[i].y * wv.y + xv[i].z * wv.z + xv[i].w * wv.w;
            }
            s[w] = a;
        }
    }
#pragma unroll
    for (int m = 1; m < 8; m <<= 1)
#pragma unroll
        for (int w = 0; w < 6; ++w) s[w] += __shfl_xor(s[w], m, 64);

    int fi0, fi1, fi2, ci0, ci1, ci2;
    float wa0, wa1, wa2, wc0, wc1, wc2;
    {
        const int n = (t0 + tl) & (N_TOK - 1);
#pragma unroll
        for (int k = 0; k < 3; ++k) {
            float pos   = (float)(n + k - 1) + s[k];
            bool  valid = (pos >= 0.0f) && (pos < (float)N_TOK);
            float ff = floorf(pos);
            ff = fminf(fmaxf(ff, 0.0f), (float)(N_TOK - 1));
            int   fi = (int)ff;
            int   ci = min(fi + 1, N_TOK - 1);
            float wc = pos - ff;
            float m  = valid ? (1.0f / (1.0f + expf(-s[3 + k]))) : 0.0f;
            float wa = (1.0f - wc) * m;
            float wcm = wc * m;
            if (k == 0) { fi0 = fi; ci0 = ci; wa0 = wa; wc0 = wcm; }
            if (k == 1) { fi1 = fi; ci1 = ci; wa1 = wa; wc1 = wcm; }
            if (k == 2) { fi2 = fi; ci2 = ci; wa2 = wa; wc2 = wcm; }
        }
    }

    // ---- ping-pong prefetch register sets (statically named) ----
    float4 pfA, pcA, pfB, pcB;
    uint4  pbA0, pbA1, pbB0, pbB1;

    auto loadgA = [&](int kk) {
        const int tap = kk >> 3;
        const int fi = (tap == 0) ? fi0 : (tap == 1 ? fi1 : fi2);
        const int ci = (tap == 0) ? ci0 : (tap == 1 ? ci1 : ci2);
        const int e0 = (kk & 7) * 32 + sub * 4;
        pfA = *(const float4*)(xb + (size_t)fi * DIM + e0);
        pcA = *(const float4*)(xb + (size_t)ci * DIM + e0);
        const uint4* g = (const uint4*)(WB2 + (size_t)kk * 8192 + (size_t)tid * 16);
        pbA0 = g[0];
        pbA1 = g[1];
    };
    auto loadgB = [&](int kk) {
        const int tap = kk >> 3;
        const int fi = (tap == 0) ? fi0 : (tap == 1 ? fi1 : fi2);
        const int ci = (tap == 0) ? ci0 : (tap == 1 ? ci1 : ci2);
        const int e0 = (kk & 7) * 32 + sub * 4;
        pfB = *(const float4*)(xb + (size_t)fi * DIM + e0);
        pcB = *(const float4*)(xb + (size_t)ci * DIM + e0);
        const uint4* g = (const uint4*)(WB2 + (size_t)kk * 8192 + (size_t)tid * 16);
        pbB0 = g[0];
        pbB1 = g[1];
    };

    auto packstoreA = [&](int buf, int kk) {
        const int tap = kk >> 3;
        const float wA = (tap == 0) ? wa0 : (tap == 1 ? wa1 : wa2);
        const float wC = (tap == 0) ? wc0 : (tap == 1 ? wc1 : wc2);
        float r0 = wA * pfA.x + wC * pcA.x;
        float r1 = wA * pfA.y + wC * pcA.y;
        float r2 = wA * pfA.z + wC * pcA.z;
        float r3 = wA * pfA.w + wC * pcA.w;
        uint32_t p0 = __builtin_amdgcn_perm(__float_as_uint(r1), __float_as_uint(r0), 0x07060302u);
        uint32_t p1 = __builtin_amdgcn_perm(__float_as_uint(r3), __float_as_uint(r2), 0x07060302u);
        *(uint2*)&As[buf][tl * 40 + sub * 4] = make_uint2(p0, p1);
        uint4* bdst = (uint4*)&Bs[buf][(tid >> 1) * 40 + (tid & 1) * 16];
        bdst[0] = pbA0;
        bdst[1] = pbA1;
    };
    auto packstoreB = [&](int buf, int kk) {
        const int tap = kk >> 3;
        const float wA = (tap == 0) ? wa0 : (tap == 1 ? wa1 : wa2);
        const float wC = (tap == 0) ? wc0 : (tap == 1 ? wc1 : wc2);
        float r0 = wA * pfB.x + wC * pcB.x;
        float r1 = wA * pfB.y + wC * pcB.y;
        float r2 = wA * pfB.z + wC * pcB.z;
        float r3 = wA * pfB.w + wC * pcB.w;
        uint32_t p0 = __builtin_amdgcn_perm(__float_as_uint(r1), __float_as_uint(r0), 0x07060302u);
        uint32_t p1 = __builtin_amdgcn_perm(__float_as_uint(r3), __float_as_uint(r2), 0x07060302u);
        *(uint2*)&As[buf][tl * 40 + sub * 4] = make_uint2(p0, p1);
        uint4* bdst = (uint4*)&Bs[buf][(tid >> 1) * 40 + (tid & 1) * 16];
        bdst[0] = pbB0;
        bdst[1] = pbB1;
    };

    floatx4 acc[2][4];
#pragma unroll
    for (int i = 0; i < 2; ++i)
#pragma unroll
        for (int j = 0; j < 4; ++j) acc[i][j] = (floatx4){0.f, 0.f, 0.f, 0.f};

    // prologue: slice 0 -> setA -> buf0; slice 1 -> setB (held in regs)
    loadgA(0);
    loadgB(1);
    packstoreA(0, 0);
    __syncthreads();                 // buf0 visible

    auto mfma_step = [&](int cur) {
        bf16x8 af[2], bfv[4];
#pragma unroll
        for (int i = 0; i < 2; ++i)
            af[i] = __builtin_bit_cast(bf16x8, *(const ushortx8*)&As[cur][(wm + i * 16 + lrow) * 40 + lq * 8]);
#pragma unroll
        for (int j = 0; j < 4; ++j)
            bfv[j] = __builtin_bit_cast(bf16x8, *(const ushortx8*)&Bs[cur][(wn + j * 16 + lrow) * 40 + lq * 8]);
#pragma unroll
        for (int i = 0; i < 2; ++i) {
            acc[i][0] = __builtin_amdgcn_mfma_f32_16x16x32_bf16(af[i], bfv[0], acc[i][0], 0, 0, 0);
            acc[i][1] = __builtin_amdgcn_mfma_f32_16x16x32_bf16(af[i], bfv[1], acc[i][1], 0, 0, 0);
            acc[i][2] = __builtin_amdgcn_mfma_f32_16x16x32_bf16(af[i], bfv[2], acc[i][2], 0, 0, 0);
            acc[i][3] = __builtin_amdgcn_mfma_f32_16x16x32_bf16(af[i], bfv[3], acc[i][3], 0, 0, 0);
        }
    };

    for (int kk = 0; kk < 24; kk += 2) {
        // ---- even sub-iter: consume buf0 (slice kk) ----
        // issue slice kk+2 loads FIRST (setA free since prev odd's packstoreA)
        if (kk < 22) loadgA(kk + 2);
        packstoreB(1, kk + 1);       // stage slice kk+1 -> buf1 (setB, loaded 1 iter ago)
        mfma_step(0);
        __syncthreads();             // drain covers loadgA: full iter body issued since

        // ---- odd sub-iter: consume buf1 (slice kk+1) ----
        if (kk < 22) {
            loadgB(kk + 3);          // issue slice kk+3 loads first
            packstoreA(0, kk + 2);   // stage slice kk+2 -> buf0 (setA, loaded 1 iter ago)
        }
        mfma_step(1);
        __syncthreads();
    }

    // ---- epilogue: C/D layout col = lane&15, row = (lane>>4)*4 + reg
#pragma unroll
    for (int i = 0; i < 2; ++i) {
#pragma unroll
        for (int r = 0; r < 4; ++r) {
            const int token = t0 + wm + i * 16 + lq * 4 + r;
            float* op = out + (size_t)token * DIM + wn + lrow;
#pragma unroll
            for (int j = 0; j < 4; ++j) op[j * 16] = acc[i][j][r];
        }
    }
}

extern "C" void kernel_launch(void* const* d_in, const int* in_sizes, int n_in,
                              void* d_out, int out_size, void* d_ws, size_t ws_size,
                              hipStream_t stream)
{
    const float* x    = (const float*)d_in[0];  // (8, 8192, 256)
    const float* offw = (const float*)d_in[1];  // (3, 256)
    const float* modw = (const float*)d_in[2];  // (3, 256)
    const float* W    = (const float*)d_in[3];  // (256, 256, 3)
    float* out = (float*)d_out;                 // (8, 8192, 256)

    const int tot_tok = 8 * N_TOK;              // 65536
    u16* WB2 = (u16*)d_ws;                      // 393,216 B fragment-linear weight

    packw_kernel<<<DIM, 256, 0, stream>>>(W, WB2);
    deform_gemm_kernel<<<tot_tok / BM, 512, 0, stream>>>(x, offw, modw, WB2, out);
}